// Round 6
// baseline (380.262 us; speedup 1.0000x reference)
//
#include <hip/hip_runtime.h>
#include <hip/hip_bf16.h>

#define BATCH 16
#define NV    20000
#define FIN   64
#define NCOUT 64
#define NK    16
#define NTILES   20000             // 16-row tiles (rows never cross a batch: 20000%16==0... NV/16=1250)
#define TPX      2500              // tiles per XCD (= 2 batches)
#define TPB      1250              // tiles per batch

typedef __attribute__((ext_vector_type(8))) short bf16x8;   // 8 bf16 (4 VGPRs)
typedef __attribute__((ext_vector_type(4))) float f32x4;

__device__ __forceinline__ short f2b(float f) {
    __hip_bfloat16 h = __float2bfloat16(f);   // RTNE
    return __builtin_bit_cast(short, h);
}

// ---------------------------------------------------------------------------
// Init: precompute per-lane MFMA B-fragments for Wx and Wn/16 into ws (16 KB).
// fragbuf[(w*8 + t*2 + h)*64 + lane] = frag; frag[j] = W[32h+quad*8+j][4m+t].
// Keeping BOTH weight frag sets in VGPRs would cost 64 regs -> occupancy 4;
// re-reading 16B/lane/frag from this L1-hot buffer keeps main-kernel VGPR<=64
// (8 blocks/CU) with zero per-tile convert VALU.
// ---------------------------------------------------------------------------
__global__ void convnet_init(const float* __restrict__ Wx,
                             const float* __restrict__ Wn,
                             short* __restrict__ fragbuf) {
    const int lane = threadIdx.x & 63;
    const int m    = lane & 15;
    const int quad = lane >> 4;
#pragma unroll
    for (int w = 0; w < 2; ++w) {
        const float* W = w ? Wn : Wx;
        const float s = w ? (1.0f / 16.0f) : 1.0f;
#pragma unroll
        for (int t = 0; t < 4; ++t) {
            const int c = 4 * m + t;
#pragma unroll
            for (int h = 0; h < 2; ++h) {
                bf16x8 fr;
#pragma unroll
                for (int j = 0; j < 8; ++j) {
                    const int f = 32 * h + quad * 8 + j;
                    fr[j] = f2b(W[f * NCOUT + c] * s);
                }
                ((bf16x8*)fragbuf)[(w * 8 + t * 2 + h) * 64 + lane] = fr;
            }
        }
    }
}

// ---------------------------------------------------------------------------
// Main: out = x@Wx + bf16(sum_k x[b, nbr[v,k]-1]) @ (Wn/16) + bias.
// NO z pass: gather x rows directly (fp32, dwordx4) and sum in fp32; one
// bf16 cast of the SUM feeds the Wn MFMA. Eliminates 82+ MB of z round-trip
// and a whole kernel. Gather instrs/row identical to the proven round-2
// gather shape (4/row), just 2x wider. x batch slice = 5.12 MB -> L2+L3
// absorb the 16x reuse (whole x = 82 MB << 256 MB L3).
// Per tile (16 rows, one wave): 16 nbr-gathers x 4 dwordx4, 4 x-loads,
// 16 frag loads (L1-hot), 16 MFMA, 4 dwordx4 stores.
// Phasing keeps peak VGPR <= 64 for 8 blocks/CU: x loads issued first
// (latency hides under gather), converted mid-gather to free the raw regs.
// ---------------------------------------------------------------------------
__global__ __launch_bounds__(256, 8) void convnet_all(
    const float* __restrict__ x,      // (320000, 64)
    const float* __restrict__ bias,   // (64)
    const int* __restrict__ nbr,      // (20000, 16), values in [0, V]
    const short* __restrict__ fragbuf,// ws, 16 KB
    float* __restrict__ out)          // (320000, 64)
{
    const int lane = threadIdx.x & 63;
    const int m    = lane & 15;
    const int quad = lane >> 4;

    float bias_q[4];
#pragma unroll
    for (int t = 0; t < 4; ++t) bias_q[t] = bias[4 * m + t];

    const bf16x8* fb = (const bf16x8*)fragbuf;

    const int xcd = blockIdx.x & 7;
    const int bi  = blockIdx.x >> 3;                    // 0..255
    const int wl  = bi * 4 + ((int)threadIdx.x >> 6);   // 0..1023
    const int WPX = (gridDim.x >> 3) * 4;               // 1024 waves/xcd

    for (int t0 = wl; t0 < TPX; t0 += WPX) {
        const int t0u = __builtin_amdgcn_readfirstlane(t0);
        const int rt  = xcd * TPX + t0u;
        const int blh = (t0u >= TPB) ? 1 : 0;
        const int b   = 2 * xcd + blh;
        const int v0  = (t0u - blh * TPB) * 16;         // in-batch first row

        // ---- issue x-row loads for the p-part (latency hides under gather)
        const float* xt =
            x + (size_t)rt * (16 * FIN) + (size_t)m * FIN + quad * 8;
        const f32x4 La0 = ((const f32x4*)xt)[0];
        const f32x4 La1 = ((const f32x4*)xt)[1];
        const f32x4 Lb0 = ((const f32x4*)(xt + 32))[0];
        const f32x4 Lb1 = ((const f32x4*)(xt + 32))[1];

        // ---- neighbor-sum gather (row m of tile; each lane owns cols
        //      quad*8..+7 of both k-halves)
        const char* xb = (const char*)x + (size_t)b * (NV * 256);
        const int coff = quad * 32;
        const int4* nb4 = (const int4*)nbr + (size_t)(v0 + m) * 4;

        f32x4 s0 = (f32x4){0.f,0.f,0.f,0.f}, s1 = s0, s2 = s0, s3 = s0;

#define GATHER1(IDX)                                                         \
        {                                                                    \
            const int idx = (IDX);                                           \
            const int sel = (idx > 0) ? (idx - 1) : 0;                       \
            const float wk = idx ? 1.0f : 0.0f;                              \
            const char* rp = xb + (size_t)((unsigned)sel * 256u + coff);     \
            const f32x4 g0 = *(const f32x4*)rp;                              \
            const f32x4 g1 = *(const f32x4*)(rp + 16);                       \
            const f32x4 g2 = *(const f32x4*)(rp + 128);                      \
            const f32x4 g3 = *(const f32x4*)(rp + 144);                      \
            s0 += wk * g0; s1 += wk * g1; s2 += wk * g2; s3 += wk * g3;      \
        }

        {
            const int4 iA = nb4[0];
            const int4 iB = nb4[1];
            GATHER1(iA.x) GATHER1(iA.y) GATHER1(iA.z) GATHER1(iA.w)
            GATHER1(iB.x) GATHER1(iB.y) GATHER1(iB.z) GATHER1(iB.w)
        }

        // convert raw x -> A frags now (frees the 16 raw-load VGPRs)
        bf16x8 af0, af1;
        af0[0] = f2b(La0.x); af0[1] = f2b(La0.y); af0[2] = f2b(La0.z); af0[3] = f2b(La0.w);
        af0[4] = f2b(La1.x); af0[5] = f2b(La1.y); af0[6] = f2b(La1.z); af0[7] = f2b(La1.w);
        af1[0] = f2b(Lb0.x); af1[1] = f2b(Lb0.y); af1[2] = f2b(Lb0.z); af1[3] = f2b(Lb0.w);
        af1[4] = f2b(Lb1.x); af1[5] = f2b(Lb1.y); af1[6] = f2b(Lb1.z); af1[7] = f2b(Lb1.w);

        {
            const int4 iC = nb4[2];
            const int4 iD = nb4[3];
            GATHER1(iC.x) GATHER1(iC.y) GATHER1(iC.z) GATHER1(iC.w)
            GATHER1(iD.x) GATHER1(iD.y) GATHER1(iD.z) GATHER1(iD.w)
        }
#undef GATHER1

        // neighbor-sum -> bf16 A frags (one rounding of the fp32 sum)
        bf16x8 an0, an1;
        an0[0] = f2b(s0.x); an0[1] = f2b(s0.y); an0[2] = f2b(s0.z); an0[3] = f2b(s0.w);
        an0[4] = f2b(s1.x); an0[5] = f2b(s1.y); an0[6] = f2b(s1.z); an0[7] = f2b(s1.w);
        an1[0] = f2b(s2.x); an1[1] = f2b(s2.y); an1[2] = f2b(s2.z); an1[3] = f2b(s2.w);
        an1[4] = f2b(s3.x); an1[5] = f2b(s3.y); an1[6] = f2b(s3.z); an1[7] = f2b(s3.w);

        // ---- 16 MFMA; B-frags streamed from the L1-hot fragbuf
        f32x4 acc[4];
#pragma unroll
        for (int t = 0; t < 4; ++t) acc[t] = (f32x4){0.f,0.f,0.f,0.f};
#pragma unroll
        for (int t = 0; t < 4; ++t) {
            acc[t] = __builtin_amdgcn_mfma_f32_16x16x32_bf16(af0, fb[(t*2 + 0)*64 + lane], acc[t], 0, 0, 0);
            acc[t] = __builtin_amdgcn_mfma_f32_16x16x32_bf16(af1, fb[(t*2 + 1)*64 + lane], acc[t], 0, 0, 0);
            acc[t] = __builtin_amdgcn_mfma_f32_16x16x32_bf16(an0, fb[(8 + t*2 + 0)*64 + lane], acc[t], 0, 0, 0);
            acc[t] = __builtin_amdgcn_mfma_f32_16x16x32_bf16(an1, fb[(8 + t*2 + 1)*64 + lane], acc[t], 0, 0, 0);
        }

        // ---- epilogue: C/D row quad*4+r, cols 4m..4m+3 -> one dwordx4/row
        const size_t rbase = (size_t)rt * 16 + quad * 4;
#pragma unroll
        for (int r = 0; r < 4; ++r) {
            const size_t orow = (rbase + r) * NCOUT + 4 * m;
            f32x4 o;
            o.x = acc[0][r] + bias_q[0];
            o.y = acc[1][r] + bias_q[1];
            o.z = acc[2][r] + bias_q[2];
            o.w = acc[3][r] + bias_q[3];
            *(f32x4*)(out + orow) = o;
        }
    }
}

extern "C" void kernel_launch(void* const* d_in, const int* in_sizes, int n_in,
                              void* d_out, int out_size, void* d_ws, size_t ws_size,
                              hipStream_t stream) {
    const float* x    = (const float*)d_in[0];
    const float* Wx   = (const float*)d_in[1];
    const float* Wn   = (const float*)d_in[2];
    const float* bias = (const float*)d_in[3];
    const int*   nbr  = (const int*)d_in[4];
    float* out = (float*)d_out;

    short* fragbuf = (short*)d_ws;   // 16 KB

    hipLaunchKernelGGL(convnet_init, dim3(1), dim3(64), 0, stream,
                       Wx, Wn, fragbuf);
    hipLaunchKernelGGL(convnet_all, dim3(2048), dim3(256), 0, stream,
                       x, bias, nbr, fragbuf, out);
}

// Round 7
// 372.149 us; speedup vs baseline: 1.0218x; 1.0218x over previous
//
#include <hip/hip_runtime.h>
#include <hip/hip_bf16.h>

#define BATCH 16
#define NV    20000
#define FIN   64
#define NCOUT 64
#define NK    16
#define TOTROWS  (BATCH * NV)      // 320000
#define NTILES   (TOTROWS / 16)    // 20000 row-tiles of 16
#define TPX      (NTILES / 8)      // 2500 tiles per XCD (= 2 batches)
#define TPB      (NV / 16)         // 1250 tiles per batch

typedef __attribute__((ext_vector_type(8))) short bf16x8;   // 8 bf16 (4 VGPRs)
typedef __attribute__((ext_vector_type(4))) float f32x4;
typedef __attribute__((ext_vector_type(4))) unsigned short u16x4;
typedef __attribute__((ext_vector_type(2))) unsigned int u32x2;

__device__ __forceinline__ short f2b(float f) {
    __hip_bfloat16 h = __float2bfloat16(f);   // RTNE
    return __builtin_bit_cast(short, h);
}

// ---------------------------------------------------------------------------
// K1: z = x @ (Wn/16), bf16, into ws. Pure streaming producer.
// Round-7: NO nontemporal hints (r5/r6 evidence: NT correlated with L2
// retention loss), 8 blocks/CU (LB(256,8), grid 2048). XCD-pinned so z lines
// are produced in the L2 that K2 consumes them from.
// ---------------------------------------------------------------------------
__global__ __launch_bounds__(256, 8) void convnet_zpass(
    const float* __restrict__ x,      // (320000, 64)
    const float* __restrict__ Wn,     // (64, 64)
    __hip_bfloat16* __restrict__ z)   // (320000, 64) bf16 [ws]
{
    const int lane = threadIdx.x & 63;
    const int m    = lane & 15;
    const int quad = lane >> 4;

    // B frags: frag[j] = Wn[k][4m + t]/16, k = 32h + quad*8 + j.
    bf16x8 bn[4][2];
#pragma unroll
    for (int t = 0; t < 4; ++t) {
        const int c = 4 * m + t;
#pragma unroll
        for (int h = 0; h < 2; ++h) {
            bf16x8 fr;
#pragma unroll
            for (int j = 0; j < 8; ++j) {
                const int f = 32 * h + quad * 8 + j;
                fr[j] = f2b(Wn[f * NCOUT + c] * (1.0f / 16.0f));
            }
            bn[t][h] = fr;
        }
    }

    const int xcd = blockIdx.x & 7;
    const int bi  = blockIdx.x >> 3;
    const int wl  = bi * 4 + ((int)threadIdx.x >> 6);
    const int WPX = (gridDim.x >> 3) * 4;              // 1024 waves/xcd

    for (int t0 = wl; t0 < TPX; t0 += WPX) {
        const int rt = __builtin_amdgcn_readfirstlane(xcd * TPX + t0);
        const float* xt =
            x + (size_t)rt * (16 * FIN) + (size_t)m * FIN + quad * 8;

        const f32x4 La0 = ((const f32x4*)xt)[0];
        const f32x4 La1 = ((const f32x4*)xt)[1];
        const f32x4 Lb0 = ((const f32x4*)(xt + 32))[0];
        const f32x4 Lb1 = ((const f32x4*)(xt + 32))[1];

        bf16x8 af0, af1;
        af0[0] = f2b(La0.x); af0[1] = f2b(La0.y); af0[2] = f2b(La0.z); af0[3] = f2b(La0.w);
        af0[4] = f2b(La1.x); af0[5] = f2b(La1.y); af0[6] = f2b(La1.z); af0[7] = f2b(La1.w);
        af1[0] = f2b(Lb0.x); af1[1] = f2b(Lb0.y); af1[2] = f2b(Lb0.z); af1[3] = f2b(Lb0.w);
        af1[4] = f2b(Lb1.x); af1[5] = f2b(Lb1.y); af1[6] = f2b(Lb1.z); af1[7] = f2b(Lb1.w);

        f32x4 acc[4];
#pragma unroll
        for (int t = 0; t < 4; ++t) acc[t] = (f32x4){0.f, 0.f, 0.f, 0.f};
#pragma unroll
        for (int t = 0; t < 4; ++t)
            acc[t] = __builtin_amdgcn_mfma_f32_16x16x32_bf16(af0, bn[t][0], acc[t], 0, 0, 0);
#pragma unroll
        for (int t = 0; t < 4; ++t)
            acc[t] = __builtin_amdgcn_mfma_f32_16x16x32_bf16(af1, bn[t][1], acc[t], 0, 0, 0);

        const size_t rbase = (size_t)rt * 16 + quad * 4;
#pragma unroll
        for (int r = 0; r < 4; ++r) {
            const size_t orow = (rbase + r) * NCOUT + 4 * m;
            u16x4 zz;
            zz.x = (unsigned short)f2b(acc[0][r]);
            zz.y = (unsigned short)f2b(acc[1][r]);
            zz.z = (unsigned short)f2b(acc[2][r]);
            zz.w = (unsigned short)f2b(acc[3][r]);
            *(u16x4*)(z + orow) = zz;
        }
    }
}

// ---------------------------------------------------------------------------
// K2: out = x@Wx + bias + gather(z).  Single out write (saves the 162 MB
// out round-trip of the 2-pass split). Round-7 fixes vs round-5's 130 µs:
//   (a) no NT hints anywhere (suspect in the +45 MB z refetch),
//   (b) 8 blocks/CU (LB(256,8), grid 2048; round-5 ran at 4 -> occ 40%),
//   (c) ascending walk matching K1's production order.
// Gather layout == MFMA C/D layout: lane (m, quad) owns rows quad*4+r,
// cols 4m..4m+3; per (r,k) one dwordx2 from z row nbr[v,k] at byte col m*8
// (wave: 4 rows x 128 B per instr — the proven round-2 shape).
// ---------------------------------------------------------------------------
__global__ __launch_bounds__(256, 8) void convnet_fused(
    const float* __restrict__ x,      // (320000, 64)
    const float* __restrict__ Wx,     // (64, 64)
    const float* __restrict__ bias,   // (64)
    const int* __restrict__ nbr,      // (20000, 16), values in [0, V]
    const __hip_bfloat16* __restrict__ z,  // (320000, 64) bf16
    float* __restrict__ out)          // (320000, 64) fp32
{
    const int lane = threadIdx.x & 63;
    const int m    = lane & 15;
    const int quad = lane >> 4;

    bf16x8 bx[4][2];
#pragma unroll
    for (int t = 0; t < 4; ++t) {
        const int c = 4 * m + t;
#pragma unroll
        for (int h = 0; h < 2; ++h) {
            bf16x8 fr;
#pragma unroll
            for (int j = 0; j < 8; ++j) {
                const int f = 32 * h + quad * 8 + j;
                fr[j] = f2b(Wx[f * NCOUT + c]);
            }
            bx[t][h] = fr;
        }
    }
    float bias_q[4];
#pragma unroll
    for (int t = 0; t < 4; ++t) bias_q[t] = bias[4 * m + t];

    const int xcd = blockIdx.x & 7;
    const int bi  = blockIdx.x >> 3;
    const int wl  = bi * 4 + ((int)threadIdx.x >> 6);
    const int WPX = (gridDim.x >> 3) * 4;              // 1024 waves/xcd

    for (int t0 = wl; t0 < TPX; t0 += WPX) {
        const int t0u = __builtin_amdgcn_readfirstlane(t0);
        const int rt  = xcd * TPX + t0u;
        const int blh = (t0u >= TPB) ? 1 : 0;
        const int b   = 2 * xcd + blh;
        const int v0  = (t0u - blh * TPB) * 16;        // in-batch first row

        const float* xt =
            x + (size_t)rt * (16 * FIN) + (size_t)m * FIN + quad * 8;
        const f32x4 La0 = ((const f32x4*)xt)[0];
        const f32x4 La1 = ((const f32x4*)xt)[1];
        const f32x4 Lb0 = ((const f32x4*)(xt + 32))[0];
        const f32x4 Lb1 = ((const f32x4*)(xt + 32))[1];

        bf16x8 af0, af1;
        af0[0] = f2b(La0.x); af0[1] = f2b(La0.y); af0[2] = f2b(La0.z); af0[3] = f2b(La0.w);
        af0[4] = f2b(La1.x); af0[5] = f2b(La1.y); af0[6] = f2b(La1.z); af0[7] = f2b(La1.w);
        af1[0] = f2b(Lb0.x); af1[1] = f2b(Lb0.y); af1[2] = f2b(Lb0.z); af1[3] = f2b(Lb0.w);
        af1[4] = f2b(Lb1.x); af1[5] = f2b(Lb1.y); af1[6] = f2b(Lb1.z); af1[7] = f2b(Lb1.w);

        f32x4 acc[4];
#pragma unroll
        for (int t = 0; t < 4; ++t) acc[t] = (f32x4){0.f, 0.f, 0.f, 0.f};
#pragma unroll
        for (int t = 0; t < 4; ++t)
            acc[t] = __builtin_amdgcn_mfma_f32_16x16x32_bf16(af0, bx[t][0], acc[t], 0, 0, 0);
#pragma unroll
        for (int t = 0; t < 4; ++t)
            acc[t] = __builtin_amdgcn_mfma_f32_16x16x32_bf16(af1, bx[t][1], acc[t], 0, 0, 0);

        // gather 16 neighbors for each of this lane's 4 rows, straight into acc
        const char* zb = (const char*)z + (size_t)b * (NV * 128);  // batch base
        const int zcol = m * 8;
#pragma unroll
        for (int r = 0; r < 4; ++r) {
            const int v = v0 + quad * 4 + r;           // in-batch row (per-lane)
            const int4* nb4 = (const int4*)nbr + (size_t)v * 4;
            const int4 i0 = nb4[0];
            const int4 i1 = nb4[1];
            const int4 i2 = nb4[2];
            const int4 i3 = nb4[3];
            int id[NK];
            id[0]  = i0.x; id[1]  = i0.y; id[2]  = i0.z; id[3]  = i0.w;
            id[4]  = i1.x; id[5]  = i1.y; id[6]  = i1.z; id[7]  = i1.w;
            id[8]  = i2.x; id[9]  = i2.y; id[10] = i2.z; id[11] = i2.w;
            id[12] = i3.x; id[13] = i3.y; id[14] = i3.z; id[15] = i3.w;

            float a0 = 0.f, a1 = 0.f, a2 = 0.f, a3 = 0.f;
#pragma unroll
            for (int k = 0; k < NK; ++k) {
                const int idx = id[k];
                int sel = idx - 1;
                sel = sel < 0 ? 0 : sel;               // clamp pad (masked below)
                const u32x2 d =
                    *(const u32x2*)(zb + (size_t)(unsigned)(sel * 128 + zcol));
                const unsigned dx = idx ? d.x : 0u;
                const unsigned dy = idx ? d.y : 0u;
                a0 += __builtin_bit_cast(float, dx << 16);
                a1 += __builtin_bit_cast(float, dx & 0xFFFF0000u);
                a2 += __builtin_bit_cast(float, dy << 16);
                a3 += __builtin_bit_cast(float, dy & 0xFFFF0000u);
            }
            acc[0][r] += a0;
            acc[1][r] += a1;
            acc[2][r] += a2;
            acc[3][r] += a3;
        }

        const size_t rbase = (size_t)rt * 16 + quad * 4;
#pragma unroll
        for (int r = 0; r < 4; ++r) {
            const size_t orow = (rbase + r) * NCOUT + 4 * m;
            f32x4 o;
            o.x = acc[0][r] + bias_q[0];
            o.y = acc[1][r] + bias_q[1];
            o.z = acc[2][r] + bias_q[2];
            o.w = acc[3][r] + bias_q[3];
            *(f32x4*)(out + orow) = o;
        }
    }
}

extern "C" void kernel_launch(void* const* d_in, const int* in_sizes, int n_in,
                              void* d_out, int out_size, void* d_ws, size_t ws_size,
                              hipStream_t stream) {
    const float* x    = (const float*)d_in[0];
    const float* Wx   = (const float*)d_in[1];
    const float* Wn   = (const float*)d_in[2];
    const float* bias = (const float*)d_in[3];
    const int*   nbr  = (const int*)d_in[4];
    float* out = (float*)d_out;

    __hip_bfloat16* z = (__hip_bfloat16*)d_ws;   // 40.96 MB (fits ws)

    hipLaunchKernelGGL(convnet_zpass, dim3(2048), dim3(256), 0, stream,
                       x, Wn, z);
    hipLaunchKernelGGL(convnet_fused, dim3(2048), dim3(256), 0, stream,
                       x, Wx, bias, nbr, z, out);
}

// Round 8
// 256.918 us; speedup vs baseline: 1.4801x; 1.4485x over previous
//
#include <hip/hip_runtime.h>
#include <hip/hip_bf16.h>

#define BATCH 16
#define NV    20000
#define FIN   64
#define NCOUT 64
#define NK    16
#define TOTROWS  (BATCH * NV)      // 320000
#define NTILES   (TOTROWS / 16)    // 20000 row-tiles of 16

typedef __attribute__((ext_vector_type(8))) short bf16x8;   // 8 bf16 (4 VGPRs)
typedef __attribute__((ext_vector_type(4))) float f32x4;    // MFMA acc
typedef __attribute__((ext_vector_type(4))) unsigned short u16x4;
typedef __attribute__((ext_vector_type(4))) unsigned int u32x4;

__device__ __forceinline__ short f2b(float f) {
    __hip_bfloat16 h = __float2bfloat16(f);   // RTNE
    return __builtin_bit_cast(short, h);
}

// ---------------------------------------------------------------------------
// Pass A: one x-sweep, MFMA 16x16x32 bf16.  (EXACT round-1 kernel — its 225-
// round config measured gemm ≈ 70 µs; round-3's group-split/XCD-pin variant
// cost +8 µs and is reverted.)
//   p[row][c] = x[row]@Wx[:,c] + bias[c]  -> out (fp32)
//   z[row][c] = x[row]@(Wn/16)            -> ws  (bf16)
// Col-tile t covers global cols {4m+t}: out = 1 dwordx4/row, z = 1 dwordx2.
// Software prefetch of next tile's raw x under current tile's MFMA+stores.
// ---------------------------------------------------------------------------
__global__ __launch_bounds__(256, 3) void convnet_gemm(
    const float* __restrict__ x,      // (320000, 64)
    const float* __restrict__ Wx,     // (64, 64)
    const float* __restrict__ Wn,     // (64, 64)
    const float* __restrict__ bias,   // (64)
    __hip_bfloat16* __restrict__ z,   // (320000, 64) bf16  [ws]
    float* __restrict__ out)          // (320000, 64) fp32  (gets p)
{
    const int lane = threadIdx.x & 63;
    const int m    = lane & 15;
    const int quad = lane >> 4;

    // B fragments: bf[t][h], t 0..3 = Wx (-> p), t 4..7 = Wn/16 (-> z).
    // frag[j] = W[k][colmap], k = 32*h + quad*8 + j, colmap = 4*m + (t&3).
    bf16x8 bf[8][2];
#pragma unroll
    for (int t = 0; t < 8; ++t) {
        const float* W = (t < 4) ? Wx : Wn;
        const float scale = (t < 4) ? 1.0f : (1.0f / 16.0f);
        const int c = 4 * m + (t & 3);
#pragma unroll
        for (int h = 0; h < 2; ++h) {
            bf16x8 fr;
#pragma unroll
            for (int j = 0; j < 8; ++j) {
                const int f = 32 * h + quad * 8 + j;
                fr[j] = f2b(W[f * NCOUT + c] * scale);
            }
            bf[t][h] = fr;
        }
    }
    float bias_q[4];
#pragma unroll
    for (int t = 0; t < 4; ++t) bias_q[t] = bias[4 * m + t];

    const int nwaves = (gridDim.x * blockDim.x) >> 6;   // 3072
    const int gw = (blockIdx.x * blockDim.x + threadIdx.x) >> 6;

    int rt = __builtin_amdgcn_readfirstlane(gw);
    const float* xt0 = x + (size_t)rt * (16 * FIN) + (size_t)m * FIN + quad * 8;
    float4 La0 = ((const float4*)xt0)[0];
    float4 La1 = ((const float4*)xt0)[1];
    float4 Lb0 = ((const float4*)(xt0 + 32))[0];
    float4 Lb1 = ((const float4*)(xt0 + 32))[1];

    for (;;) {
        bf16x8 af0, af1;
        af0[0] = f2b(La0.x); af0[1] = f2b(La0.y); af0[2] = f2b(La0.z); af0[3] = f2b(La0.w);
        af0[4] = f2b(La1.x); af0[5] = f2b(La1.y); af0[6] = f2b(La1.z); af0[7] = f2b(La1.w);
        af1[0] = f2b(Lb0.x); af1[1] = f2b(Lb0.y); af1[2] = f2b(Lb0.z); af1[3] = f2b(Lb0.w);
        af1[4] = f2b(Lb1.x); af1[5] = f2b(Lb1.y); af1[6] = f2b(Lb1.z); af1[7] = f2b(Lb1.w);

        const int rtn = rt + nwaves;
        const bool more = rtn < NTILES;
        float4 Na0, Na1, Nb0, Nb1;
        if (more) {
            const float* xn = x + (size_t)rtn * (16 * FIN) + (size_t)m * FIN + quad * 8;
            Na0 = ((const float4*)xn)[0];
            Na1 = ((const float4*)xn)[1];
            Nb0 = ((const float4*)(xn + 32))[0];
            Nb1 = ((const float4*)(xn + 32))[1];
        }

        f32x4 acc[8];
#pragma unroll
        for (int t = 0; t < 8; ++t) acc[t] = (f32x4){0.f, 0.f, 0.f, 0.f};
#pragma unroll
        for (int t = 0; t < 8; ++t)
            acc[t] = __builtin_amdgcn_mfma_f32_16x16x32_bf16(af0, bf[t][0], acc[t], 0, 0, 0);
#pragma unroll
        for (int t = 0; t < 8; ++t)
            acc[t] = __builtin_amdgcn_mfma_f32_16x16x32_bf16(af1, bf[t][1], acc[t], 0, 0, 0);

        const size_t rbase = (size_t)rt * 16 + quad * 4;
#pragma unroll
        for (int r = 0; r < 4; ++r) {
            const size_t orow = (rbase + r) * NCOUT + 4 * m;
            float4 o;
            o.x = acc[0][r] + bias_q[0];
            o.y = acc[1][r] + bias_q[1];
            o.z = acc[2][r] + bias_q[2];
            o.w = acc[3][r] + bias_q[3];
            *(float4*)(out + orow) = o;
            u16x4 zz;
            zz.x = (unsigned short)f2b(acc[4][r]);
            zz.y = (unsigned short)f2b(acc[5][r]);
            zz.z = (unsigned short)f2b(acc[6][r]);
            zz.w = (unsigned short)f2b(acc[7][r]);
            *(u16x4*)(z + orow) = zz;
        }

        if (!more) break;
        rt = __builtin_amdgcn_readfirstlane(rtn);
        La0 = Na0; La1 = Na1; Lb0 = Nb0; Lb1 = Nb1;
    }
}

// ---------------------------------------------------------------------------
// Pass B: out[b,v,:] += sum_k z[b, nbr[v,k]-1, :]  (idx==0 = zero pad).
// ROUND-8 CHANGE (one lever): 16 B/lane gathers. Wave = 8 consecutive rows;
// lane = (s = lane>>3 sub-row, c = lane&7 col-group of 8 bf16). Each gather
// instr covers 8 z-rows x 128 B = 1 KB (the max) -> gather instr count
// halves vs round 3 (1.28M -> 640K), attacking the TA-issue component.
// Traffic identical; per-byte VALU identical; out RMW read issued early.
// XCD pinning kept (2 batches per XCD, one live 2.56 MB z window per L2).
// ---------------------------------------------------------------------------
__global__ __launch_bounds__(256, 8) void convnet_gather(
    const int* __restrict__ nbr,           // (20000, 16), values in [0, V]
    const __hip_bfloat16* __restrict__ z,  // (320000, 64) bf16
    float* __restrict__ out)               // (320000, 64) fp32, has p already
{
    const int lane = threadIdx.x & 63;
    const int s    = lane >> 3;            // sub-row 0..7
    const int c    = lane & 7;             // col group (8 bf16 = 16 B)
    const int xcd  = blockIdx.x & 7;
    const int bi   = blockIdx.x >> 3;                        // 0..255
    const int wl   = bi * 4 + ((int)threadIdx.x >> 6);       // 0..1023
    const int WPX  = (gridDim.x >> 3) * 4;                   // 1024 waves/xcd

    const int zcol   = c * 16;             // byte col offset (8 bf16)
    const int GROUPS = (2 * NV) / 8;       // 5000 groups per xcd

    for (int g = wl; g < GROUPS; g += WPX) {
        const int gu = __builtin_amdgcn_readfirstlane(g);
        const int bl = (gu >= NV / 8) ? 1 : 0;
        const int b  = 2 * xcd + bl;
        const int v0 = gu * 8 - bl * NV;
        const int row0 = b * NV + v0;      // global out row of sub-row 0

        // out RMW read issued early: HBM miss hides under the gathers below.
        float* op = out + (size_t)(row0 + s) * NCOUT + 8 * c;
        f32x4 o0 = ((f32x4*)op)[0];
        f32x4 o1 = ((f32x4*)op)[1];

        // neighbor ids for this lane's sub-row: 4x int4 (one 64B line/row).
        const int4* nb4 =
            (const int4*)((const char*)nbr + (size_t)(v0 + s) * (NK * 4));
        const int4 i0 = nb4[0];
        const int4 i1 = nb4[1];
        const int4 i2 = nb4[2];
        const int4 i3 = nb4[3];
        int id[NK];
        id[0]  = i0.x; id[1]  = i0.y; id[2]  = i0.z; id[3]  = i0.w;
        id[4]  = i1.x; id[5]  = i1.y; id[6]  = i1.z; id[7]  = i1.w;
        id[8]  = i2.x; id[9]  = i2.y; id[10] = i2.z; id[11] = i2.w;
        id[12] = i3.x; id[13] = i3.y; id[14] = i3.z; id[15] = i3.w;

        const char* zb = (const char*)z + (size_t)b * (NV * 128);  // batch base
        float a0 = 0.f, a1 = 0.f, a2 = 0.f, a3 = 0.f;
        float a4 = 0.f, a5 = 0.f, a6 = 0.f, a7 = 0.f;
#pragma unroll
        for (int k = 0; k < NK; ++k) {
            const int idx = id[k];
            int sel = idx - 1;
            sel = sel < 0 ? 0 : sel;       // clamp pad (row 0 read, masked)
            const u32x4 d =
                *(const u32x4*)(zb + (size_t)(unsigned)(sel * 128 + zcol));
            const unsigned d0 = idx ? d.x : 0u;
            const unsigned d1 = idx ? d.y : 0u;
            const unsigned d2 = idx ? d.z : 0u;
            const unsigned d3 = idx ? d.w : 0u;
            a0 += __builtin_bit_cast(float, d0 << 16);
            a1 += __builtin_bit_cast(float, d0 & 0xFFFF0000u);
            a2 += __builtin_bit_cast(float, d1 << 16);
            a3 += __builtin_bit_cast(float, d1 & 0xFFFF0000u);
            a4 += __builtin_bit_cast(float, d2 << 16);
            a5 += __builtin_bit_cast(float, d2 & 0xFFFF0000u);
            a6 += __builtin_bit_cast(float, d3 << 16);
            a7 += __builtin_bit_cast(float, d3 & 0xFFFF0000u);
        }

        o0.x += a0; o0.y += a1; o0.z += a2; o0.w += a3;
        o1.x += a4; o1.y += a5; o1.z += a6; o1.w += a7;
        ((f32x4*)op)[0] = o0;
        ((f32x4*)op)[1] = o1;
    }
}

extern "C" void kernel_launch(void* const* d_in, const int* in_sizes, int n_in,
                              void* d_out, int out_size, void* d_ws, size_t ws_size,
                              hipStream_t stream) {
    const float* x    = (const float*)d_in[0];
    const float* Wx   = (const float*)d_in[1];
    const float* Wn   = (const float*)d_in[2];
    const float* bias = (const float*)d_in[3];
    const int*   nbr  = (const int*)d_in[4];
    float* out = (float*)d_out;

    __hip_bfloat16* z = (__hip_bfloat16*)d_ws;   // 40.96 MB (fits ws)

    hipLaunchKernelGGL(convnet_gemm, dim3(768), dim3(256), 0, stream,
                       x, Wx, Wn, bias, z, out);
    hipLaunchKernelGGL(convnet_gather, dim3(2048), dim3(256), 0, stream,
                       nbr, z, out);
}

// Round 9
// 223.215 us; speedup vs baseline: 1.7036x; 1.1510x over previous
//
#include <hip/hip_runtime.h>
#include <hip/hip_bf16.h>

#define BATCH 16
#define NV    20000
#define FIN   64
#define NCOUT 64
#define NK    16
#define TOTROWS  (BATCH * NV)      // 320000
#define NTILES   (TOTROWS / 16)    // 20000 row-tiles of 16

typedef __attribute__((ext_vector_type(8))) short bf16x8;   // 8 bf16 (4 VGPRs)
typedef __attribute__((ext_vector_type(4))) float f32x4;    // MFMA acc / NT ld-st
typedef __attribute__((ext_vector_type(4))) unsigned short u16x4;
typedef __attribute__((ext_vector_type(2))) unsigned int u32x2;

__device__ __forceinline__ short f2b(float f) {
    __hip_bfloat16 h = __float2bfloat16(f);   // RTNE
    return __builtin_bit_cast(short, h);
}

// ---------------------------------------------------------------------------
// Pass A: one x-sweep, MFMA 16x16x32 bf16.  (EXACT round-1 kernel — best
// measured config: grid 768, LB(256,3), prefetch pipeline, ~70 µs.)
//   p[row][c] = x[row]@Wx[:,c] + bias[c]  -> out (fp32)
//   z[row][c] = x[row]@(Wn/16)            -> ws  (bf16)
// Col-tile t covers global cols {4m+t}: out = 1 dwordx4/row, z = 1 dwordx2.
// ---------------------------------------------------------------------------
__global__ __launch_bounds__(256, 3) void convnet_gemm(
    const float* __restrict__ x,      // (320000, 64)
    const float* __restrict__ Wx,     // (64, 64)
    const float* __restrict__ Wn,     // (64, 64)
    const float* __restrict__ bias,   // (64)
    __hip_bfloat16* __restrict__ z,   // (320000, 64) bf16  [ws]
    float* __restrict__ out)          // (320000, 64) fp32  (gets p)
{
    const int lane = threadIdx.x & 63;
    const int m    = lane & 15;
    const int quad = lane >> 4;

    bf16x8 bf[8][2];
#pragma unroll
    for (int t = 0; t < 8; ++t) {
        const float* W = (t < 4) ? Wx : Wn;
        const float scale = (t < 4) ? 1.0f : (1.0f / 16.0f);
        const int c = 4 * m + (t & 3);
#pragma unroll
        for (int h = 0; h < 2; ++h) {
            bf16x8 fr;
#pragma unroll
            for (int j = 0; j < 8; ++j) {
                const int f = 32 * h + quad * 8 + j;
                fr[j] = f2b(W[f * NCOUT + c] * scale);
            }
            bf[t][h] = fr;
        }
    }
    float bias_q[4];
#pragma unroll
    for (int t = 0; t < 4; ++t) bias_q[t] = bias[4 * m + t];

    const int nwaves = (gridDim.x * blockDim.x) >> 6;   // 3072
    const int gw = (blockIdx.x * blockDim.x + threadIdx.x) >> 6;

    int rt = __builtin_amdgcn_readfirstlane(gw);
    const float* xt0 = x + (size_t)rt * (16 * FIN) + (size_t)m * FIN + quad * 8;
    float4 La0 = ((const float4*)xt0)[0];
    float4 La1 = ((const float4*)xt0)[1];
    float4 Lb0 = ((const float4*)(xt0 + 32))[0];
    float4 Lb1 = ((const float4*)(xt0 + 32))[1];

    for (;;) {
        bf16x8 af0, af1;
        af0[0] = f2b(La0.x); af0[1] = f2b(La0.y); af0[2] = f2b(La0.z); af0[3] = f2b(La0.w);
        af0[4] = f2b(La1.x); af0[5] = f2b(La1.y); af0[6] = f2b(La1.z); af0[7] = f2b(La1.w);
        af1[0] = f2b(Lb0.x); af1[1] = f2b(Lb0.y); af1[2] = f2b(Lb0.z); af1[3] = f2b(Lb0.w);
        af1[4] = f2b(Lb1.x); af1[5] = f2b(Lb1.y); af1[6] = f2b(Lb1.z); af1[7] = f2b(Lb1.w);

        const int rtn = rt + nwaves;
        const bool more = rtn < NTILES;
        float4 Na0, Na1, Nb0, Nb1;
        if (more) {
            const float* xn = x + (size_t)rtn * (16 * FIN) + (size_t)m * FIN + quad * 8;
            Na0 = ((const float4*)xn)[0];
            Na1 = ((const float4*)xn)[1];
            Nb0 = ((const float4*)(xn + 32))[0];
            Nb1 = ((const float4*)(xn + 32))[1];
        }

        f32x4 acc[8];
#pragma unroll
        for (int t = 0; t < 8; ++t) acc[t] = (f32x4){0.f, 0.f, 0.f, 0.f};
#pragma unroll
        for (int t = 0; t < 8; ++t)
            acc[t] = __builtin_amdgcn_mfma_f32_16x16x32_bf16(af0, bf[t][0], acc[t], 0, 0, 0);
#pragma unroll
        for (int t = 0; t < 8; ++t)
            acc[t] = __builtin_amdgcn_mfma_f32_16x16x32_bf16(af1, bf[t][1], acc[t], 0, 0, 0);

        const size_t rbase = (size_t)rt * 16 + quad * 4;
#pragma unroll
        for (int r = 0; r < 4; ++r) {
            const size_t orow = (rbase + r) * NCOUT + 4 * m;
            float4 o;
            o.x = acc[0][r] + bias_q[0];
            o.y = acc[1][r] + bias_q[1];
            o.z = acc[2][r] + bias_q[2];
            o.w = acc[3][r] + bias_q[3];
            *(float4*)(out + orow) = o;
            u16x4 zz;
            zz.x = (unsigned short)f2b(acc[4][r]);
            zz.y = (unsigned short)f2b(acc[5][r]);
            zz.z = (unsigned short)f2b(acc[6][r]);
            zz.w = (unsigned short)f2b(acc[7][r]);
            *(u16x4*)(z + orow) = zz;
        }

        if (!more) break;
        rt = __builtin_amdgcn_readfirstlane(rtn);
        La0 = Na0; La1 = Na1; Lb0 = Nb0; Lb1 = Nb1;
    }
}

// ---------------------------------------------------------------------------
// Pass B: out[b,v,:] += sum_k z[b, nbr[v,k]-1, :]  (idx==0 = zero pad).
// EXACT round-3 shape (its best: 70.8 µs, WRITE=80, z-refetch 1.14x):
// wave = 4 rows, lane = (s=lane>>4, c=lane&15), dwordx2 gathers, one
// contiguous f32x4 store/lane (wave store = 1 KB, full lines — round-8's
// strided 2-store layout caused 2.4x write amplification and is reverted).
// ROUND-9 SINGLE LEVER: nontemporal hints on the OUT stream only (RMW read
// + store). out is 160 MB of read-once/write-once traffic that was evicting
// the 2.56 MB z gather window; NT keeps it out of L2 so z (the only reused
// data) retains the cache. z and nbr loads stay cached.
// ---------------------------------------------------------------------------
__global__ __launch_bounds__(256, 6) void convnet_gather(
    const int* __restrict__ nbr,           // (20000, 16), values in [0, V]
    const __hip_bfloat16* __restrict__ z,  // (320000, 64) bf16
    float* __restrict__ out)               // (320000, 64) fp32, has p already
{
    const int lane = threadIdx.x & 63;
    const int s    = lane >> 4;            // sub-row 0..3
    const int c    = lane & 15;            // col group (4 bf16 = 8 B)
    const int xcd  = blockIdx.x & 7;
    const int bi   = blockIdx.x >> 3;                        // 0..191
    const int wl   = bi * 4 + ((int)threadIdx.x >> 6);       // 0..767
    const int WPX  = (gridDim.x >> 3) * 4;                   // 768 waves/xcd

    const int zcol   = c * 8;              // byte col offset (4 bf16)
    const int GROUPS = (2 * NV) / 4;       // 10000 groups per xcd

    for (int g = wl; g < GROUPS; g += WPX) {
        const int gu = __builtin_amdgcn_readfirstlane(g);
        const int bl = (gu >= NV / 4) ? 1 : 0;
        const int b  = 2 * xcd + bl;
        const int v0 = gu * 4 - bl * NV;
        const int row0 = b * NV + v0;      // global out row of sub-row 0

        // out RMW read issued early (NT: no L2 allocate — protects z window);
        // HBM miss latency hides under the 16 gathers below.
        f32x4* op = (f32x4*)(out + (size_t)(row0 + s) * NCOUT + 4 * c);
        f32x4 ov = __builtin_nontemporal_load(op);

        // neighbor ids for this lane's sub-row: 4x int4 (one 64B line/row).
        const int4* nb4 =
            (const int4*)((const char*)nbr + (size_t)(v0 + s) * (NK * 4));
        const int4 i0 = nb4[0];
        const int4 i1 = nb4[1];
        const int4 i2 = nb4[2];
        const int4 i3 = nb4[3];
        int id[NK];
        id[0]  = i0.x; id[1]  = i0.y; id[2]  = i0.z; id[3]  = i0.w;
        id[4]  = i1.x; id[5]  = i1.y; id[6]  = i1.z; id[7]  = i1.w;
        id[8]  = i2.x; id[9]  = i2.y; id[10] = i2.z; id[11] = i2.w;
        id[12] = i3.x; id[13] = i3.y; id[14] = i3.z; id[15] = i3.w;

        const char* zb = (const char*)z + (size_t)b * (NV * 128);  // batch base
        float a0 = 0.f, a1 = 0.f, a2 = 0.f, a3 = 0.f;
#pragma unroll
        for (int k = 0; k < NK; ++k) {
            const int idx = id[k];
            int sel = idx - 1;
            sel = sel < 0 ? 0 : sel;       // clamp pad (row 0 read, masked)
            const u32x2 d =
                *(const u32x2*)(zb + (size_t)(unsigned)(sel * 128 + zcol));
            const unsigned dx = idx ? d.x : 0u;
            const unsigned dy = idx ? d.y : 0u;
            a0 += __builtin_bit_cast(float, dx << 16);
            a1 += __builtin_bit_cast(float, dx & 0xFFFF0000u);
            a2 += __builtin_bit_cast(float, dy << 16);
            a3 += __builtin_bit_cast(float, dy & 0xFFFF0000u);
        }

        ov.x += a0; ov.y += a1; ov.z += a2; ov.w += a3;
        __builtin_nontemporal_store(ov, op);   // wave = 1 KB contiguous
    }
}

extern "C" void kernel_launch(void* const* d_in, const int* in_sizes, int n_in,
                              void* d_out, int out_size, void* d_ws, size_t ws_size,
                              hipStream_t stream) {
    const float* x    = (const float*)d_in[0];
    const float* Wx   = (const float*)d_in[1];
    const float* Wn   = (const float*)d_in[2];
    const float* bias = (const float*)d_in[3];
    const int*   nbr  = (const int*)d_in[4];
    float* out = (float*)d_out;

    __hip_bfloat16* z = (__hip_bfloat16*)d_ws;   // 40.96 MB (fits ws)

    hipLaunchKernelGGL(convnet_gemm, dim3(768), dim3(256), 0, stream,
                       x, Wx, Wn, bias, z, out);
    hipLaunchKernelGGL(convnet_gather, dim3(1536), dim3(256), 0, stream,
                       nbr, z, out);
}